// Round 4
// baseline (109.117 us; speedup 1.0000x reference)
//
#include <hip/hip_runtime.h>
#include <hip/hip_bf16.h>

// out[b] = adj @ (x[b] @ W) + bias ; B=64, N=4096, F_IN=F_OUT=32
// R19: KILL THE ADJ-CVT PREP PASS — GEMM reg-stages A from f32 adj directly.
//   Post-mortems R16/R18: both 8-wave phase restructures regressed (39-40%
//   MfmaUtil vs 46-48%) -> the 2-phase/4-wave/2-blocks-per-CU structure is
//   the proven local optimum; cross-block drift is the latency hider.
//   R17's region swizzle cut FETCH 82->65.6MB (keep it).
//   Remaining cost split: GEMM 60.7us + prep 32.7us. Prep's adj cvt moves
//   96MB of HBM traffic just to enable gload_lds on A. This round: GEMM
//   loads A f32 (coalesced dwordx4, issued at loop top), converts f2bf
//   in-register AFTER the MFMA block (T14 issue-early/write-late), writes
//   swizzled ds_write_b128 (write-side XOR == proven read-side XOR).
//   B path (St bf16, pre-swizzled source + gload_lds) unchanged.
//   Prep shrinks to support-only (48MB, ~9us). +32 VGPR (112->~150), still
//   2 blk/CU. VALUBusy 24% has headroom for the ~130 cvt insts/thread/tile.
// ws needs only St (16MB); ws>=50.4MB proven (R10).

#define B_SZ 64
#define N_SZ 4096
#define NT 64

typedef __attribute__((ext_vector_type(8))) short bf16x8;
typedef __attribute__((ext_vector_type(4))) float f32x4;
typedef __attribute__((ext_vector_type(8))) unsigned short u16x8;

__device__ __forceinline__ unsigned short f2bf(float f) {
  unsigned int u = __float_as_uint(f);
  u += 0x7fffu + ((u >> 16) & 1u);
  return (unsigned short)(u >> 16);
}

// ---------------- prep: support = x @ W -> bf16, o-major [2048][4096] -------
__global__ __launch_bounds__(256) void k_support(const float* __restrict__ x,
                                                 const float* __restrict__ W,
                                                 unsigned short* __restrict__ St) {
  const int gid = blockIdx.x * 256 + threadIdx.x;
  const int m = gid & (N_SZ - 1);
  const int b = gid >> 12;
  const float4* xr = (const float4*)(x + (size_t)gid * 32);
  float xv[32];
#pragma unroll
  for (int i = 0; i < 8; ++i) {
    float4 v = xr[i];
    xv[4 * i + 0] = v.x; xv[4 * i + 1] = v.y;
    xv[4 * i + 2] = v.z; xv[4 * i + 3] = v.w;
  }
  const size_t obase = ((size_t)b * 32) * (size_t)N_SZ + m;
#pragma unroll
  for (int o = 0; o < 32; ++o) {
    float acc = 0.f;
#pragma unroll
    for (int f = 0; f < 32; ++f) acc = fmaf(xv[f], W[f * 32 + o], acc);
    St[obase + (size_t)o * N_SZ] = f2bf(acc);
  }
}

// -- GEMM: 128x128, 4 waves (2M x 2KS, wave 64x128), dbuf 64KB, 2 blk/CU -----
//    A: reg-staged from f32 adj (cvt in-register, swizzled ds_write).
//    B: St bf16 via pre-swizzled-source gload_lds (proven).
#define GLOAD16(gp, lp)                                                        \
  __builtin_amdgcn_global_load_lds(                                            \
      (const __attribute__((address_space(1))) void*)(gp),                     \
      (__attribute__((address_space(3))) void*)(lp), 16, 0, 0)
#define PRIO1() __builtin_amdgcn_s_setprio(1)
#define PRIO0() __builtin_amdgcn_s_setprio(0)

__global__ __launch_bounds__(256, 2) void k_gemm7(const float* __restrict__ adj,
                                                  const unsigned short* __restrict__ Bm,
                                                  const float* __restrict__ bias,
                                                  float* __restrict__ out) {
  __shared__ __attribute__((aligned(16))) char SM[65536];
  char* Lc = SM;            // current tile buf: [A 16KB][B 16KB]
  char* Lo = SM + 32768;    // other buf
  const int t = threadIdx.x;
  const int wg = blockIdx.x;
  const int xcd = wg & 7;
  const int idx = wg >> 3;
  // L2-region mapping (R17-proven): XCD owns a 1024x1024 C-region, 8x8 tiles.
  const int bm0 = ((xcd >> 1) << 10) + ((idx >> 3) << 7);
  const int bn0 = ((xcd & 1) << 10) + ((idx & 7) << 7);
  const int lane = t & 63;
  const int wid = t >> 6;          // 0..3
  const int wr = wid & 1;          // M-half (64 rows)
  const int ks = wid >> 1;         // split-K team: kk-half of BK=64

  f32x4 acc[4][8];
#pragma unroll
  for (int i = 0; i < 4; ++i)
#pragma unroll
    for (int j = 0; j < 8; ++j) acc[i][j] = (f32x4){0.f, 0.f, 0.f, 0.f};

  // ---- B staging: 4 gloads/tile, pre-swizzled global source (rule #21) ----
  const int srow = t >> 3;   // 0..31
  const int as = t & 7;
  const int swz = (as ^ (srow & 7)) << 4;
  const size_t b_s0 = ((size_t)(bn0 + srow) << 13) + (size_t)swz;
  const int t16 = t * 16;
  const char* B8 = (const char*)Bm;

#define STAGE_B(KT_, Ld)                                                       \
  do {                                                                         \
    const size_t kb = (size_t)(KT_) << 7;                                      \
    GLOAD16(B8 + b_s0 + kb,          (Ld) + 16384 + t16);                      \
    GLOAD16(B8 + b_s0 + 262144 + kb, (Ld) + 20480 + t16);                      \
    GLOAD16(B8 + b_s0 + 524288 + kb, (Ld) + 24576 + t16);                      \
    GLOAD16(B8 + b_s0 + 786432 + kb, (Ld) + 28672 + t16);                      \
  } while (0)

  // ---- A staging: f32 reg-load -> f2bf -> swizzled ds_write_b128 ----------
  // thread t, j=0..3: row = j*32 + (t>>3), k-chunk ch = t&7 (8 elems).
  // per-instr coalescing: 8 lanes cover 256B contiguous per row, 8 rows/instr.
  const float* aF = adj + ((size_t)(bm0 + (t >> 3)) << 12) + ((t & 7) << 3);
  // write offset: row*128 + ((ch ^ (row&7))<<4); row&7 == (t>>3)&7 (j*32%8==0)
  const int awbase = ((t >> 3) << 7) + (((t & 7) ^ ((t >> 3) & 7)) << 4);

#define ALOAD(KT_)                                                             \
  do {                                                                         \
    const float* ap_ = aF + ((size_t)(KT_) << 6);                              \
    _Pragma("unroll") for (int j = 0; j < 4; ++j) {                            \
      va[2 * j]     = *(const float4*)(ap_ + (size_t)j * 131072);              \
      va[2 * j + 1] = *(const float4*)(ap_ + (size_t)j * 131072 + 4);          \
    }                                                                          \
  } while (0)

#define AWRITE(Ld)                                                             \
  do {                                                                         \
    _Pragma("unroll") for (int j = 0; j < 4; ++j) {                            \
      u16x8 w_;                                                                \
      w_[0] = f2bf(va[2 * j].x);     w_[1] = f2bf(va[2 * j].y);                \
      w_[2] = f2bf(va[2 * j].z);     w_[3] = f2bf(va[2 * j].w);                \
      w_[4] = f2bf(va[2 * j + 1].x); w_[5] = f2bf(va[2 * j + 1].y);            \
      w_[6] = f2bf(va[2 * j + 1].z); w_[7] = f2bf(va[2 * j + 1].w);            \
      *(u16x8*)((Ld) + awbase + j * 4096) = w_;                                \
    }                                                                          \
  } while (0)

  // fragment LDS byte offsets (kk = ks per team; XOR swizzle, proven)
  const int cbase = (ks * 64 + ((lane >> 4) << 4)) ^ ((lane & 7) << 4);
  int aoff[4], boff[8];
#pragma unroll
  for (int mi = 0; mi < 4; ++mi)
    aoff[mi] = (wr * 64 + mi * 16 + (lane & 15)) * 128 + cbase;
#pragma unroll
  for (int ni = 0; ni < 8; ++ni)
    boff[ni] = 16384 + (ni * 16 + (lane & 15)) * 128 + cbase;

  float4 va[8];

  // prologue: tile 0 into buf0
  ALOAD(0);
  STAGE_B(0, Lc);
  AWRITE(Lc);
  __syncthreads();  // drains B DMA + publishes A writes

  for (int kt = 0; kt < NT; ++kt) {
    // 1) issue next tile's loads first (max latency cover)
    if (kt + 1 < NT) {
      ALOAD(kt + 1);
      STAGE_B(kt + 1, Lo);
    }
    // 2) team frag reads (A 4 + B 8 = 12 ds_read_b128)
    bf16x8 a[4], b[8];
#pragma unroll
    for (int mi = 0; mi < 4; ++mi) a[mi] = *(const bf16x8*)(Lc + aoff[mi]);
#pragma unroll
    for (int ni = 0; ni < 8; ++ni) b[ni] = *(const bf16x8*)(Lc + boff[ni]);
    // 3) 32 MFMA (team's kk-half, 64x128 wave tile)
    PRIO1();
#pragma unroll
    for (int mi = 0; mi < 4; ++mi)
#pragma unroll
      for (int ni = 0; ni < 8; ++ni)
        acc[mi][ni] = __builtin_amdgcn_mfma_f32_16x16x32_bf16(
            a[mi], b[ni], acc[mi][ni], 0, 0, 0);
    PRIO0();
    // 4) cvt + write A for next tile (loads have had frag+MFMA time to land)
    if (kt + 1 < NT) AWRITE(Lo);
    // 5) barrier (drains B DMA + A ds_writes; covered by sibling block)
    __syncthreads();
    { char* tp_ = Lc; Lc = Lo; Lo = tp_; }
  }

  // ------- split-K merge through LDS (dbuf is dead now; 32KB per ks1-wave) --
  if (ks == 1) {
    char* mb = SM + (wr << 15);
#pragma unroll
    for (int mi = 0; mi < 4; ++mi)
#pragma unroll
      for (int ni = 0; ni < 8; ++ni)
        *(f32x4*)(mb + (((mi * 8 + ni) << 6) + lane) * 16) = acc[mi][ni];
  }
  __syncthreads();
  if (ks == 0) {
    char* mb = SM + (wr << 15);
#pragma unroll
    for (int mi = 0; mi < 4; ++mi)
#pragma unroll
      for (int ni = 0; ni < 8; ++ni)
        acc[mi][ni] += *(const f32x4*)(mb + (((mi * 8 + ni) << 6) + lane) * 16);
    // ---- epilogue: C/D layout col=lane&15, row=(lane>>4)*4+q (proven) ----
    const float blo = bias[lane & 15];
    const float bhi = bias[(lane & 15) + 16];
#pragma unroll
    for (int mi = 0; mi < 4; ++mi) {
#pragma unroll
      for (int ni = 0; ni < 8; ++ni) {
        const float badd = (ni & 1) ? bhi : blo;
#pragma unroll
        for (int q = 0; q < 4; ++q) {
          const int n = bm0 + wr * 64 + mi * 16 + ((lane >> 4) << 2) + q;
          const int cidx = bn0 + ni * 16 + (lane & 15);
          const int bb = cidx >> 5;
          const int o = cidx & 31;
          out[(((size_t)bb << 12) + n) * 32 + o] = acc[mi][ni][q] + badd;
        }
      }
    }
  }
}

extern "C" void kernel_launch(void* const* d_in, const int* in_sizes, int n_in,
                              void* d_out, int out_size, void* d_ws, size_t ws_size,
                              hipStream_t stream) {
  const float* x = (const float*)d_in[0];
  const float* adj = (const float*)d_in[1];
  const float* W = (const float*)d_in[2];
  const float* bias = (const float*)d_in[3];
  float* out = (float*)d_out;

  // workspace: St only = 2048*4096*2B = 16MB (ws>=50.4MB proven R10)
  unsigned short* St = (unsigned short*)d_ws;

  hipLaunchKernelGGL(k_support, dim3((B_SZ * N_SZ) / 256), dim3(256), 0, stream,
                     x, W, St);
  hipLaunchKernelGGL(k_gemm7, dim3(512), dim3(256), 0, stream, adj, St, bias,
                     out);
}

// Round 5
// 90.107 us; speedup vs baseline: 1.2110x; 1.2110x over previous
//
#include <hip/hip_runtime.h>
#include <hip/hip_bf16.h>

// out[b] = adj @ (x[b] @ W) + bias ; B=64, N=4096, F_IN=F_OUT=32
// R20: REVERT GEMM TO R17 (proven 60.5us) + FIX SUPPORT'S 2B SCATTERED STORES.
//   Post-mortem R19: f32 reg-staged A cratered GEMM (127us, MfmaUtil 21.7) -
//   in-loop cvt+ds_write+vmcnt drain on the critical path; gload_lds bf16 path
//   is structurally 2x better. R16/R18/R19 all confirm: R17's GEMM structure
//   (128^2, 4 waves 2wr x 2ks, dbuf, 2 blk/CU, single-sync loop) is the local
//   optimum. Remaining gap is prep: 33us vs 23us ideal (144MB @ 6.3TB/s).
//   Support wrote 32 scalar 2B stores/thread (G13 violation, partial L2
//   sectors). Fix: LDS transpose [256][33] (pad -> ~2-way conflicts) then
//   cooperative u16x8 stores - each wave instr writes 2 contiguous 512B
//   row-segments. cvt body already optimal; k_prep fusion kept.
// ws>=50.4MB proven (R10); half-split fallback kept.

#define B_SZ 64
#define N_SZ 4096
#define NT 64

typedef __attribute__((ext_vector_type(8))) short bf16x8;
typedef __attribute__((ext_vector_type(4))) float f32x4;
typedef __attribute__((ext_vector_type(8))) unsigned short u16x8;

__device__ __forceinline__ unsigned short f2bf(float f) {
  unsigned int u = __float_as_uint(f);
  u += 0x7fffu + ((u >> 16) & 1u);
  return (unsigned short)(u >> 16);
}

// ---- support: x @ W -> bf16 St[o-major 2048][4096], 16B-coalesced stores ---
__device__ __forceinline__ void support_body_lds(const float* __restrict__ x,
                                                 const float* __restrict__ W,
                                                 unsigned short* __restrict__ St,
                                                 int sbid, int t,
                                                 unsigned short* __restrict__ L) {
  const int b = sbid >> 4;            // 16 blocks per batch row
  const int m0 = (sbid & 15) << 8;    // 256-node range
  const int gid = (sbid << 8) + t;    // = b*4096 + m0 + t
  const float4* xr = (const float4*)(x + (size_t)gid * 32);
  float xv[32];
#pragma unroll
  for (int i = 0; i < 8; ++i) {
    float4 v = xr[i];
    xv[4 * i + 0] = v.x; xv[4 * i + 1] = v.y;
    xv[4 * i + 2] = v.z; xv[4 * i + 3] = v.w;
  }
  // acc over o, park bf16 in padded LDS [256][33]
#pragma unroll
  for (int o = 0; o < 32; ++o) {
    float acc = 0.f;
#pragma unroll
    for (int f = 0; f < 32; ++f) acc = fmaf(xv[f], W[f * 32 + o], acc);
    L[t * 33 + o] = f2bf(acc);
  }
  __syncthreads();
  // cooperative stores: iter it, thread t -> o = it*8 + (t>>5), m-seg (t&31)*8
  const int l32 = t & 31;
#pragma unroll
  for (int it = 0; it < 4; ++it) {
    const int o = it * 8 + (t >> 5);
    u16x8 w;
#pragma unroll
    for (int i = 0; i < 8; ++i) w[i] = L[(l32 * 8 + i) * 33 + o];
    *(u16x8*)(St + ((size_t)(b * 32 + o) << 12) + m0 + l32 * 8) = w;
  }
}

__device__ __forceinline__ void cvt_body(const float* __restrict__ a,
                                         unsigned short* __restrict__ o,
                                         size_t idx8) {
  const size_t i = idx8 * 8;
  const float4* p = (const float4*)(a + i);
  float4 v0 = p[0], v1 = p[1];
  u16x8 r;
  r[0] = f2bf(v0.x); r[1] = f2bf(v0.y); r[2] = f2bf(v0.z); r[3] = f2bf(v0.w);
  r[4] = f2bf(v1.x); r[5] = f2bf(v1.y); r[6] = f2bf(v1.z); r[7] = f2bf(v1.w);
  *(u16x8*)(o + i) = r;
}

// ---------------- prep: fused full-adj cvt + support (full path) ------------
__global__ __launch_bounds__(256) void k_prep(const float* __restrict__ x,
                                              const float* __restrict__ adj,
                                              const float* __restrict__ W,
                                              unsigned short* __restrict__ St,
                                              unsigned short* __restrict__ adjB) {
  __shared__ unsigned short L[256 * 33];
  const int bid = blockIdx.x;
  const int t = threadIdx.x;
  if (bid < 8192) cvt_body(adj, adjB, (size_t)bid * 256 + t);
  else support_body_lds(x, W, St, bid - 8192, t, L);
}

// fallback-path kernels
__global__ __launch_bounds__(256) void k_support(const float* __restrict__ x,
                                                 const float* __restrict__ W,
                                                 unsigned short* __restrict__ St) {
  __shared__ unsigned short L[256 * 33];
  support_body_lds(x, W, St, blockIdx.x, threadIdx.x, L);
}
__global__ __launch_bounds__(256) void k_cvt(const float* __restrict__ a,
                                             unsigned short* __restrict__ o) {
  cvt_body(a, o, (size_t)blockIdx.x * 256 + threadIdx.x);
}

// -- GEMM: 128x128, 4 waves (2M x 2KS, wave 64x128), dbuf 64KB, 2 blk/CU -----
#define GLOAD16(gp, lp)                                                        \
  __builtin_amdgcn_global_load_lds(                                            \
      (const __attribute__((address_space(1))) void*)(gp),                     \
      (__attribute__((address_space(3))) void*)(lp), 16, 0, 0)
#define PRIO1() __builtin_amdgcn_s_setprio(1)
#define PRIO0() __builtin_amdgcn_s_setprio(0)

__global__ __launch_bounds__(256, 2) void k_gemm6(const unsigned short* __restrict__ Ab,
                                                  const unsigned short* __restrict__ Bm,
                                                  const float* __restrict__ bias,
                                                  float* __restrict__ out,
                                                  int nbm, int rowoff) {
  __shared__ __attribute__((aligned(16))) char SM[65536];
  char* Lc = SM;            // current tile buf: [A 16KB][B 16KB]
  char* Lo = SM + 32768;    // other buf
  const int t = threadIdx.x;
  const int wg = blockIdx.x;
  const int xcd = wg & 7;
  const int idx = wg >> 3;
  int bm0, bn0;
  if (nbm == 4) {
    // full path: XCD region = 1024x1024 (rm = xcd>>1, rn = xcd&1), 8x8 tiles.
    bm0 = ((xcd >> 1) << 10) + ((idx >> 3) << 7);
    bn0 = ((xcd & 1) << 10) + ((idx & 7) << 7);
  } else {
    // fallback half-split path
    bm0 = (xcd * nbm + (idx >> 4)) << 7;
    bn0 = (idx & 15) << 7;
  }
  const int lane = t & 63;
  const int wid = t >> 6;          // 0..3
  const int wr = wid & 1;          // M-half (64 rows)
  const int ks = wid >> 1;         // split-K team: kk-half of BK=64

  f32x4 acc[4][8];
#pragma unroll
  for (int i = 0; i < 4; ++i)
#pragma unroll
    for (int j = 0; j < 8; ++j) acc[i][j] = (f32x4){0.f, 0.f, 0.f, 0.f};

  // staging: 8 gloads/tile (A 4 + B 4), each 256thr x 16B = 4KB = 32 rows
  const int srow = t >> 3;   // 0..31
  const int as = t & 7;
  const int swz = (as ^ (srow & 7)) << 4;  // inverse-swizzled source (rule #21)
  const size_t a_s0 = ((size_t)(bm0 + srow) << 13) + (size_t)swz;
  const size_t b_s0 = ((size_t)(bn0 + srow) << 13) + (size_t)swz;
  const int t16 = t * 16;
  const char* A8 = (const char*)Ab;
  const char* B8 = (const char*)Bm;

#define STAGE(KT_, Ld)                                                         \
  do {                                                                         \
    const size_t kb = (size_t)(KT_) << 7;                                      \
    GLOAD16(A8 + a_s0 + kb,          (Ld) + t16);                              \
    GLOAD16(A8 + a_s0 + 262144 + kb, (Ld) + 4096 + t16);                       \
    GLOAD16(A8 + a_s0 + 524288 + kb, (Ld) + 8192 + t16);                       \
    GLOAD16(A8 + a_s0 + 786432 + kb, (Ld) + 12288 + t16);                      \
    GLOAD16(B8 + b_s0 + kb,          (Ld) + 16384 + t16);                      \
    GLOAD16(B8 + b_s0 + 262144 + kb, (Ld) + 20480 + t16);                      \
    GLOAD16(B8 + b_s0 + 524288 + kb, (Ld) + 24576 + t16);                      \
    GLOAD16(B8 + b_s0 + 786432 + kb, (Ld) + 28672 + t16);                      \
  } while (0)

  // fragment LDS byte offsets (kk = ks per team; XOR swizzle, R10-proven)
  const int cbase = (ks * 64 + ((lane >> 4) << 4)) ^ ((lane & 7) << 4);
  int aoff[4], boff[8];
#pragma unroll
  for (int mi = 0; mi < 4; ++mi)
    aoff[mi] = (wr * 64 + mi * 16 + (lane & 15)) * 128 + cbase;
#pragma unroll
  for (int ni = 0; ni < 8; ++ni)
    boff[ni] = 16384 + (ni * 16 + (lane & 15)) * 128 + cbase;

  // prologue: tile 0 into buf0
  STAGE(0, Lc);
  __syncthreads();  // drains the 8 DMA loads

  for (int kt = 0; kt < NT; ++kt) {
    // 1) issue next tile's DMA first (max latency cover before the sync)
    if (kt + 1 < NT) STAGE(kt + 1, Lo);
    // 2) team frag reads (A 4 + B 8 = 12 ds_read_b128)
    bf16x8 a[4], b[8];
#pragma unroll
    for (int mi = 0; mi < 4; ++mi) a[mi] = *(const bf16x8*)(Lc + aoff[mi]);
#pragma unroll
    for (int ni = 0; ni < 8; ++ni) b[ni] = *(const bf16x8*)(Lc + boff[ni]);
    // 3) 32 MFMA (team's kk-half, 64x128 wave tile)
    PRIO1();
#pragma unroll
    for (int mi = 0; mi < 4; ++mi)
#pragma unroll
      for (int ni = 0; ni < 8; ++ni)
        acc[mi][ni] = __builtin_amdgcn_mfma_f32_16x16x32_bf16(
            a[mi], b[ni], acc[mi][ni], 0, 0, 0);
    PRIO0();
    // 4) barrier (drains DMA; covered by sibling block / other waves)
    __syncthreads();
    { char* tp_ = Lc; Lc = Lo; Lo = tp_; }
  }

  // ------- split-K merge through LDS (dbuf is dead now; 32KB per ks1-wave) --
  if (ks == 1) {
    char* mb = SM + (wr << 15);
#pragma unroll
    for (int mi = 0; mi < 4; ++mi)
#pragma unroll
      for (int ni = 0; ni < 8; ++ni)
        *(f32x4*)(mb + (((mi * 8 + ni) << 6) + lane) * 16) = acc[mi][ni];
  }
  __syncthreads();
  if (ks == 0) {
    char* mb = SM + (wr << 15);
#pragma unroll
    for (int mi = 0; mi < 4; ++mi)
#pragma unroll
      for (int ni = 0; ni < 8; ++ni)
        acc[mi][ni] += *(const f32x4*)(mb + (((mi * 8 + ni) << 6) + lane) * 16);
    // ---- epilogue: C/D layout col=lane&15, row=(lane>>4)*4+q (proven) ----
    const float blo = bias[lane & 15];
    const float bhi = bias[(lane & 15) + 16];
#pragma unroll
    for (int mi = 0; mi < 4; ++mi) {
#pragma unroll
      for (int ni = 0; ni < 8; ++ni) {
        const float badd = (ni & 1) ? bhi : blo;
#pragma unroll
        for (int q = 0; q < 4; ++q) {
          const int n = rowoff + bm0 + wr * 64 + mi * 16 + ((lane >> 4) << 2) + q;
          const int cidx = bn0 + ni * 16 + (lane & 15);
          const int bb = cidx >> 5;
          const int o = cidx & 31;
          out[(((size_t)bb << 12) + n) * 32 + o] = acc[mi][ni][q] + badd;
        }
      }
    }
  }
}

extern "C" void kernel_launch(void* const* d_in, const int* in_sizes, int n_in,
                              void* d_out, int out_size, void* d_ws, size_t ws_size,
                              hipStream_t stream) {
  const float* x = (const float*)d_in[0];
  const float* adj = (const float*)d_in[1];
  const float* W = (const float*)d_in[2];
  const float* bias = (const float*)d_in[3];
  float* out = (float*)d_out;

  const size_t ST_B = (size_t)2048 * 4096 * 2;      // 16,777,216
  const size_t ADJ_FULL = (size_t)4096 * 4096 * 2;  // 33,554,432

  unsigned short* St = (unsigned short*)d_ws;

  if (ws_size >= ST_B + ADJ_FULL) {
    // full path (proven to run): fused prep + one GEMM (grid 512 = 2 blk/CU)
    unsigned short* adjB = St + (ST_B / 2);
    hipLaunchKernelGGL(k_prep, dim3(9216), dim3(256), 0, stream, x, adj, W, St,
                       adjB);
    hipLaunchKernelGGL(k_gemm6, dim3(512), dim3(256), 0, stream, adjB, St, bias,
                       out, 4, 0);
  } else {
    // fallback half-split (not expected to run): one 2048-row panel reused
    unsigned short* adjH = St + (ST_B / 2);
    hipLaunchKernelGGL(k_support, dim3((B_SZ * N_SZ) / 256), dim3(256), 0,
                       stream, x, W, St);
    hipLaunchKernelGGL(k_cvt, dim3((2048 * 4096) / 2048), dim3(256), 0, stream,
                       adj, adjH);
    hipLaunchKernelGGL(k_gemm6, dim3(256), dim3(256), 0, stream, adjH, St, bias,
                       out, 2, 0);
    hipLaunchKernelGGL(k_cvt, dim3((2048 * 4096) / 2048), dim3(256), 0, stream,
                       adj + (size_t)2048 * 4096, adjH);
    hipLaunchKernelGGL(k_gemm6, dim3(256), dim3(256), 0, stream, adjH, St, bias,
                       out, 2, 2048);
  }
}